// Round 1
// baseline (363.838 us; speedup 1.0000x reference)
//
#include <hip/hip_runtime.h>
#include <math.h>

#define C 128
#define N 1024
#define EPS 1e-6f

__global__ __launch_bounds__(128) void rlsa_kernel(
    const float* __restrict__ feat,
    const float* __restrict__ wq, const float* __restrict__ bq,
    const float* __restrict__ wk, const float* __restrict__ bk,
    const float* __restrict__ wv, const float* __restrict__ bv,
    float* __restrict__ out_rlsa, float* __restrict__ out_ri,
    float* __restrict__ out_si)
{
    __shared__ float xs[C];
    __shared__ float ks[C];
    __shared__ float vs[C];
    __shared__ float wsum[2];

    const int tid = threadIdx.x;
    const int bid = blockIdx.x;            // flat row index b*N + n
    const int b = bid >> 10;               // / 1024
    const int n = bid & 1023;

    // load x row: x[b,n,c] = feat[b,c,n]  (strided gather, only 512 B/row)
    xs[tid] = feat[(size_t)b * C * N + (size_t)tid * N + n];
    __syncthreads();

    // thread `tid` computes q/k/v channel `tid`: dot(x, w[tid,:]) + b[tid]
    const float4* wq4 = (const float4*)(wq + tid * C);
    const float4* wk4 = (const float4*)(wk + tid * C);
    const float4* wv4 = (const float4*)(wv + tid * C);
    const float4* x4  = (const float4*)xs;
    float aq = 0.f, ak = 0.f, av = 0.f;
    #pragma unroll
    for (int j = 0; j < C / 4; ++j) {
        float4 xv = x4[j];
        float4 q = wq4[j];
        float4 k = wk4[j];
        float4 v = wv4[j];
        aq += xv.x * q.x + xv.y * q.y + xv.z * q.z + xv.w * q.w;
        ak += xv.x * k.x + xv.y * k.y + xv.z * k.z + xv.w * k.w;
        av += xv.x * v.x + xv.y * v.y + xv.z * v.z + xv.w * v.w;
    }
    aq += bq[tid];
    ak += bk[tid];
    av += bv[tid];

    // feature map: elu(t)+1 = t+1 (t>0) else exp(t)
    float qf = aq > 0.f ? aq + 1.f : expf(aq);
    float kf = ak > 0.f ? ak + 1.f : expf(ak);
    float vf = av;

    ks[tid] = kf;
    vs[tid] = vf;

    // S = sum_c q_c * k_c  (block reduction: wave64 shuffle, then combine 2 waves)
    float p = qf * kf;
    #pragma unroll
    for (int off = 32; off > 0; off >>= 1) p += __shfl_down(p, off, 64);
    if ((tid & 63) == 0) wsum[tid >> 6] = p;
    __syncthreads();
    const float S = wsum[0] + wsum[1];
    const float coef = S / (S + EPS);   // Z * S

    // Si and RLSA rows (coalesced)
    out_si[(size_t)bid * C + tid]   = kf;
    out_rlsa[(size_t)bid * C + tid] = coef * vf;

    // Ri[c][m] = k_c * v_m, 16384 floats/row, fully-coalesced float4 stores.
    // float4 index f4 = i*128 + tid -> c = f4>>5 = i*4 + tid/32, m = 4*(tid&31)
    float4* ri4 = (float4*)(out_ri + (size_t)bid * C * C);
    const float4* vs4 = (const float4*)vs;
    const int mq = tid & 31;
    const int chi = tid >> 5;
    #pragma unroll
    for (int i = 0; i < 32; ++i) {
        const float kc = ks[i * 4 + chi];
        float4 vv = vs4[mq];
        ri4[i * 128 + tid] = make_float4(kc * vv.x, kc * vv.y, kc * vv.z, kc * vv.w);
    }
}

extern "C" void kernel_launch(void* const* d_in, const int* in_sizes, int n_in,
                              void* d_out, int out_size, void* d_ws, size_t ws_size,
                              hipStream_t stream) {
    const float* feat = (const float*)d_in[0];
    const float* wq   = (const float*)d_in[1];
    const float* bq   = (const float*)d_in[2];
    const float* wk   = (const float*)d_in[3];
    const float* bk   = (const float*)d_in[4];
    const float* wv   = (const float*)d_in[5];
    const float* bv   = (const float*)d_in[6];

    float* out  = (float*)d_out;
    float* rlsa = out;                                   // 4*1024*128
    float* ri   = out + (size_t)4 * 1024 * 128;          // 4*1024*128*128
    float* si   = ri  + (size_t)4 * 1024 * 128 * 128;    // 4*1024*128

    rlsa_kernel<<<4096, 128, 0, stream>>>(feat, wq, bq, wk, bk, wv, bv,
                                          rlsa, ri, si);
}

// Round 2
// 296.172 us; speedup vs baseline: 1.2285x; 1.2285x over previous
//
#include <hip/hip_runtime.h>
#include <math.h>

#define C 128
#define N 1024
#define EPS 1e-6f

// ---------------- Kernel A: QKV + feature map + S-reduction + Si/RLSA ----
// 16 rows per block, 256 threads. Thread t: channel c = t&127, row-half h = t>>7
// (rows h*8 .. h*8+7 of the tile). x tile staged in LDS as xs[j][nlocal],
// stride 20 floats (80 B -> 16B-aligned float4 reads, wave-broadcast).
#define TR 16          // rows per block
#define XS_STRIDE 20   // floats; 80 B row stride keeps float4 reads aligned

__global__ __launch_bounds__(256) void qkv_kernel(
    const float* __restrict__ feat,
    const float* __restrict__ wq, const float* __restrict__ bq,
    const float* __restrict__ wk, const float* __restrict__ bk,
    const float* __restrict__ wv, const float* __restrict__ bv,
    float* __restrict__ out_rlsa, float* __restrict__ out_si,
    float* __restrict__ ws_v)
{
    __shared__ float xs[C * XS_STRIDE];      // 10 KB
    __shared__ float sred[4][8];             // per-wave row partial sums

    const int t    = threadIdx.x;
    const int c    = t & 127;
    const int half = t >> 7;                 // 0: rows 0..7, 1: rows 8..15
    const int row0 = blockIdx.x * TR;        // flat row = b*N + n; TR | N so no batch straddle
    const int b    = row0 >> 10;
    const int n0   = row0 & 1023;

    // ---- stage x tile: xs[j*XS_STRIDE + nl] = feat[b][j][n0+nl] ----
    {
        const float* fb = feat + (size_t)b * C * N;
        #pragma unroll
        for (int f = t; f < 512; f += 256) {       // 512 float4 loads total
            int j = f >> 2, q = f & 3;
            float4 v = *(const float4*)(fb + (size_t)j * N + n0 + q * 4);
            *(float4*)&xs[j * XS_STRIDE + q * 4] = v;
        }
    }
    __syncthreads();

    // ---- dot products: acc[m][i] for rows r = half*8 + i ----
    float aq[8] = {0}, ak[8] = {0}, av[8] = {0};
    const float4* wq4 = (const float4*)(wq + c * C);
    const float4* wk4 = (const float4*)(wk + c * C);
    const float4* wv4 = (const float4*)(wv + c * C);
    const int xoff = half * 8;

    #pragma unroll 8
    for (int j4 = 0; j4 < 32; ++j4) {
        float4 q4 = wq4[j4];
        float4 k4 = wk4[j4];
        float4 v4 = wv4[j4];
        #pragma unroll
        for (int u = 0; u < 4; ++u) {
            const float* xr = &xs[(j4 * 4 + u) * XS_STRIDE + xoff];
            float4 xa = *(const float4*)(xr);
            float4 xb = *(const float4*)(xr + 4);
            float wqv = (u == 0) ? q4.x : (u == 1) ? q4.y : (u == 2) ? q4.z : q4.w;
            float wkv = (u == 0) ? k4.x : (u == 1) ? k4.y : (u == 2) ? k4.z : k4.w;
            float wvv = (u == 0) ? v4.x : (u == 1) ? v4.y : (u == 2) ? v4.z : v4.w;
            aq[0] += xa.x * wqv; aq[1] += xa.y * wqv; aq[2] += xa.z * wqv; aq[3] += xa.w * wqv;
            aq[4] += xb.x * wqv; aq[5] += xb.y * wqv; aq[6] += xb.z * wqv; aq[7] += xb.w * wqv;
            ak[0] += xa.x * wkv; ak[1] += xa.y * wkv; ak[2] += xa.z * wkv; ak[3] += xa.w * wkv;
            ak[4] += xb.x * wkv; ak[5] += xb.y * wkv; ak[6] += xb.z * wkv; ak[7] += xb.w * wkv;
            av[0] += xa.x * wvv; av[1] += xa.y * wvv; av[2] += xa.z * wvv; av[3] += xa.w * wvv;
            av[4] += xb.x * wvv; av[5] += xb.y * wvv; av[6] += xb.z * wvv; av[7] += xb.w * wvv;
        }
    }

    const float bqc = bq[c], bkc = bk[c], bvc = bv[c];
    float qf[8], kf[8], vf[8];
    #pragma unroll
    for (int i = 0; i < 8; ++i) {
        float q = aq[i] + bqc;
        float k = ak[i] + bkc;
        qf[i] = q > 0.f ? q + 1.f : expf(q);
        kf[i] = k > 0.f ? k + 1.f : expf(k);
        vf[i] = av[i] + bvc;
    }

    // ---- per-row S = sum_c qf*kf : wave shuffle, combine 2 waves/row-half ----
    const int wave = t >> 6;
    const int lane = t & 63;
    #pragma unroll
    for (int i = 0; i < 8; ++i) {
        float p = qf[i] * kf[i];
        #pragma unroll
        for (int off = 32; off > 0; off >>= 1) p += __shfl_down(p, off, 64);
        if (lane == 0) sred[wave][i] = p;
    }
    __syncthreads();

    // ---- stores: Si, RLSA, V-stash (coalesced: lanes span consecutive c) ----
    #pragma unroll
    for (int i = 0; i < 8; ++i) {
        float S = sred[half * 2][i] + sred[half * 2 + 1][i];
        float coef = S / (S + EPS);
        size_t ro = (size_t)(row0 + half * 8 + i) * C + c;
        out_si[ro]   = kf[i];
        out_rlsa[ro] = coef * vf[i];
        ws_v[ro]     = vf[i];
    }
}

// ---------------- Kernel B: Ri[row][c][m] = kf[c] * vf[m]  (pure stream) ----
#define BROWS 4

__global__ __launch_bounds__(256) void ri_kernel(
    const float* __restrict__ si, const float* __restrict__ ws_v,
    float* __restrict__ out_ri)
{
    __shared__ float ks[BROWS * C];
    __shared__ float vs[BROWS * C];

    const int t  = threadIdx.x;
    const int r0 = blockIdx.x * BROWS;

    #pragma unroll
    for (int idx = t; idx < BROWS * C; idx += 256) {
        int rr = idx >> 7, cc = idx & 127;
        ks[idx] = si[(size_t)(r0 + rr) * C + cc];
        vs[idx] = ws_v[(size_t)(r0 + rr) * C + cc];
    }
    __syncthreads();

    const float4* vs4 = (const float4*)vs;
    #pragma unroll
    for (int rr = 0; rr < BROWS; ++rr) {
        float4* ri4 = (float4*)(out_ri + (size_t)(r0 + rr) * C * C);
        const float* krow = ks + rr * C;
        const float4* vrow4 = vs4 + rr * 32;
        #pragma unroll
        for (int i = 0; i < 16; ++i) {
            int f4 = i * 256 + t;
            float kc = krow[f4 >> 5];
            float4 vv = vrow4[f4 & 31];
            ri4[f4] = make_float4(kc * vv.x, kc * vv.y, kc * vv.z, kc * vv.w);
        }
    }
}

extern "C" void kernel_launch(void* const* d_in, const int* in_sizes, int n_in,
                              void* d_out, int out_size, void* d_ws, size_t ws_size,
                              hipStream_t stream) {
    const float* feat = (const float*)d_in[0];
    const float* wq   = (const float*)d_in[1];
    const float* bq   = (const float*)d_in[2];
    const float* wk   = (const float*)d_in[3];
    const float* bk   = (const float*)d_in[4];
    const float* wv   = (const float*)d_in[5];
    const float* bv   = (const float*)d_in[6];

    float* out  = (float*)d_out;
    float* rlsa = out;                                   // 4*1024*128
    float* ri   = out + (size_t)4 * 1024 * 128;          // 4*1024*128*128
    float* si   = ri  + (size_t)4 * 1024 * 128 * 128;    // 4*1024*128

    float* ws_v = (float*)d_ws;                          // 4*1024*128 V stash

    qkv_kernel<<<4096 / TR, 256, 0, stream>>>(feat, wq, bq, wk, bk, wv, bv,
                                              rlsa, si, ws_v);
    ri_kernel<<<4096 / BROWS, 256, 0, stream>>>(si, ws_v, ri);
}